// Round 3
// baseline (271.800 us; speedup 1.0000x reference)
//
#include <hip/hip_runtime.h>

// Problem constants
#define BDIM   16
#define PDIM   12
#define TDIM   4096
#define WINW   41
#define PADW   20
#define DDIM   492      // P*WIN
#define DPAD   512      // padded K for MFMA (zeros beyond 492)
#define KCODES 1024
#define KSTEPS 16       // 512 / 32
#define NTILES 64       // 1024 / 16

#define WAVES      4                 // 256-thread blocks
#define ROWS_WAVE  32                // 2 slabs of 16 rows
#define BMROWS     (WAVES * ROWS_WAVE)    // 128 rows per block
#define NHALF      2                 // code-range split across blockIdx.y
#define NT_HALF    (NTILES / NHALF)  // 32 ntiles per sweep
#define NT_BYTES   (KSTEPS * 64 * 16)     // 16384 bytes per ntile

#define MROWS      (BDIM * TDIM)     // 65536

typedef __attribute__((ext_vector_type(8))) short  short8;  // 8 x bf16 (4 VGPRs)
typedef __attribute__((ext_vector_type(4))) float  f32x4;   // MFMA acc

__device__ __forceinline__ unsigned short f2bf(float f) {
    union { float f; unsigned int u; } v; v.f = f;
    unsigned int r = v.u + 0x7FFFu + ((v.u >> 16) & 1u);  // round-to-nearest-even
    return (unsigned short)(r >> 16);
}

// Pre-format codebook into B-fragment order for mfma_f32_16x16x32_bf16.
// frag idx = (nt*16 + ks)*64 + lane, 8 bf16 each:
//   B[k][n], n = nt*16 + (lane&15), k = ks*32 + (lane>>4)*8 + j
__global__ __launch_bounds__(256) void prep_bfrag_k(const float* __restrict__ cb,
                                                    unsigned short* __restrict__ bfrag) {
    int idx  = blockIdx.x * 256 + threadIdx.x;   // 0 .. 65535
    int lane = idx & 63;
    int ks   = (idx >> 6) & 15;
    int nt   = idx >> 10;
    int n    = nt * 16 + (lane & 15);
    int hi   = lane >> 4;
    short8 sv;
#pragma unroll
    for (int j = 0; j < 8; ++j) {
        int k = ks * 32 + hi * 8 + j;
        float f = (k < DDIM) ? cb[n * DDIM + k] : 0.f;
        sv[j] = (short)f2bf(f);
    }
    *(short8*)(bfrag + (size_t)idx * 8) = sv;
}

__global__ __launch_bounds__(64) void prep_cnorm_k(const float* __restrict__ cb,
                                                   float* __restrict__ cnorm) {
    int n = blockIdx.x;
    int lane = threadIdx.x;
    float s = 0.f;
    for (int d = lane; d < DDIM; d += 64) { float c = cb[n * DDIM + d]; s += c * c; }
#pragma unroll
    for (int m = 1; m < 64; m <<= 1) s += __shfl_xor(s, m, 64);
    if (lane == 0) cnorm[n] = s;
}

// Exact sum of ||f||^2 over all rows, via window multiplicity:
// mult(tt) = 41 - max(0,20-tt) - max(0,tt-4075). Per-block f32 partials.
__global__ __launch_bounds__(256) void xsq_k(const float* __restrict__ x,
                                             float* __restrict__ xsq_part) {
    float s = 0.f;
    for (int i = blockIdx.x * 256 + threadIdx.x; i < BDIM * PDIM * TDIM; i += 256 * 256) {
        int tt = i & (TDIM - 1);
        int mult = WINW - max(0, PADW - tt) - max(0, tt - (TDIM - 1 - PADW));
        float v = x[i];
        s += (float)mult * v * v;
    }
#pragma unroll
    for (int m = 1; m < 64; m <<= 1) s += __shfl_xor(s, m, 64);
    __shared__ float sm[4];
    if ((threadIdx.x & 63) == 0) sm[threadIdx.x >> 6] = s;
    __syncthreads();
    if (threadIdx.x == 0) xsq_part[blockIdx.x] = sm[0] + sm[1] + sm[2] + sm[3];
}

// Stage one 16 KiB ntile of bfrag into LDS (async, width 16, linear).
__device__ __forceinline__ void stage_nt(const unsigned short* __restrict__ bfrag,
                                         unsigned char* smem_buf, int nt,
                                         int wave, int lane) {
    const unsigned char* gsrc = (const unsigned char*)bfrag + (size_t)nt * NT_BYTES;
#pragma unroll
    for (int it = 0; it < 4; ++it) {
        int off = it * 4096 + wave * 1024;
        __builtin_amdgcn_global_load_lds(
            (const __attribute__((address_space(1))) unsigned int*)(gsrc + off + lane * 16),
            (__attribute__((address_space(3))) unsigned int*)(smem_buf + off),
            16, 0, 0);
    }
}

// Main sweep: block = 4 waves x 32 rows = 128 rows; blockIdx.y picks a
// 512-code half. Track per-row MAX score s = f.c - 0.5*||c||^2 only
// (dist = ||f||^2 - 2*smax); no index, no recompute. Row maxes -> ws.
__global__ __launch_bounds__(256, 3) void vq_main_k(const float* __restrict__ x,
                                                    const unsigned short* __restrict__ bfrag,
                                                    const float* __restrict__ cnorm,
                                                    float* __restrict__ rowmax) {
    __shared__ unsigned char smem[2][NT_BYTES];

    const int lane = threadIdx.x & 63;
    const int wave = threadIdx.x >> 6;
    const int ld   = lane & 15;
    const int hi   = lane >> 4;
    const int by   = blockIdx.y;
    const int nt0  = by * NT_HALF;
    const int rowbase = blockIdx.x * BMROWS + wave * ROWS_WAVE;

    // Kick off staging of first ntile; A-build overlaps the load latency.
    stage_nt(bfrag, smem[0], nt0, wave, lane);

    // ---- Build A fragments for 2 slabs (row = rowbase + s*16 + ld) ----
    short8 afr[2][KSTEPS];
#pragma unroll
    for (int s = 0; s < 2; ++s) {
        int m = rowbase + s * 16 + ld;
        int b = m >> 12;            // / TDIM
        int t = m & (TDIM - 1);
        const float* xb = x + (size_t)b * (PDIM * TDIM);
#pragma unroll
        for (int ks = 0; ks < KSTEPS; ++ks) {
            short8 a;
#pragma unroll
            for (int j = 0; j < 8; ++j) {
                int d = ks * 32 + hi * 8 + j;
                float v = 0.f;
                if (d < DDIM) {
                    int p  = d / WINW;
                    int w  = d - p * WINW;
                    int tt = t + w - PADW;
                    if (tt >= 0 && tt < TDIM) v = xb[p * TDIM + tt];
                }
                a[j] = (short)f2bf(v);
            }
            afr[s][ks] = a;
        }
    }

    float bs[2][4];
#pragma unroll
    for (int s = 0; s < 2; ++s)
#pragma unroll
        for (int r = 0; r < 4; ++r) bs[s][r] = -3.0e38f;

    __syncthreads();   // ntile 0 resident (barrier drains vmcnt)

    // ---- Sweep this half's 32 ntiles, double-buffered 1-ntile chunks ----
    for (int c = 0; c < NT_HALF; ++c) {
        if (c + 1 < NT_HALF) stage_nt(bfrag, smem[(c + 1) & 1], nt0 + c + 1, wave, lane);
        const unsigned char* cur = smem[c & 1];
        f32x4 acc0 = {0.f, 0.f, 0.f, 0.f};
        f32x4 acc1 = {0.f, 0.f, 0.f, 0.f};
        const short8* bp = (const short8*)cur + lane;
#pragma unroll
        for (int ks = 0; ks < KSTEPS; ++ks) {
            short8 bfr = bp[ks * 64];
            acc0 = __builtin_amdgcn_mfma_f32_16x16x32_bf16(afr[0][ks], bfr, acc0, 0, 0, 0);
            acc1 = __builtin_amdgcn_mfma_f32_16x16x32_bf16(afr[1][ks], bfr, acc1, 0, 0, 0);
        }
        const float sb = -0.5f * cnorm[(nt0 + c) * 16 + ld];
#pragma unroll
        for (int r = 0; r < 4; ++r) {           // D: col(N)=lane&15, row(M)=hi*4+r
            float s0 = acc0[r] + sb;
            float s1 = acc1[r] + sb;
            bs[0][r] = fmaxf(bs[0][r], s0);
            bs[1][r] = fmaxf(bs[1][r], s1);
        }
        __syncthreads();   // staging of c+1 done; all waves done reading cur
    }

    // ---- Max across the 16 lanes of each group (masks stay in-group) ----
#pragma unroll
    for (int msk = 1; msk < 16; msk <<= 1) {
#pragma unroll
        for (int s = 0; s < 2; ++s)
#pragma unroll
            for (int r = 0; r < 4; ++r)
                bs[s][r] = fmaxf(bs[s][r], __shfl_xor(bs[s][r], msk, 64));
    }

    // Lane ld==0 of each 16-lane group owns rows [rowbase + s*16 + hi*4 .. +3]
    if (ld == 0) {
        float* dst = rowmax + (size_t)by * MROWS + rowbase + hi * 4;
#pragma unroll
        for (int s = 0; s < 2; ++s) {
            float4 v = make_float4(bs[s][0], bs[s][1], bs[s][2], bs[s][3]);
            *(float4*)(dst + s * 16) = v;
        }
    }
}

// loss = 0.25 * (Sxx - 2*sum_rows max_half(rowmax)) / (65536*492)
__global__ __launch_bounds__(1024) void finalize_k(const float* __restrict__ rowmax,
                                                   const float* __restrict__ xsq_part,
                                                   float* __restrict__ out) {
    __shared__ double sm[1024];
    float s = 0.f;
    for (int r = threadIdx.x; r < MROWS; r += 1024)
        s += fmaxf(rowmax[r], rowmax[MROWS + r]);
    sm[threadIdx.x] = (double)s;
    __syncthreads();
    for (int st = 512; st > 0; st >>= 1) {
        if ((int)threadIdx.x < st) sm[threadIdx.x] += sm[threadIdx.x + st];
        __syncthreads();
    }
    if (threadIdx.x == 0) {
        double sxx = 0.0;
        for (int i = 0; i < 256; ++i) sxx += (double)xsq_part[i];
        double sdist = sxx - 2.0 * sm[0];
        out[0] = (float)(0.25 * sdist / ((double)MROWS * (double)DDIM));
    }
}

extern "C" void kernel_launch(void* const* d_in, const int* in_sizes, int n_in,
                              void* d_out, int out_size, void* d_ws, size_t ws_size,
                              hipStream_t stream) {
    const float* x  = (const float*)d_in[0];   // (16,12,4096) f32
    const float* cb = (const float*)d_in[1];   // (1024,492) f32
    float* out = (float*)d_out;

    // workspace layout (~1.55 MiB)
    char* ws = (char*)d_ws;
    unsigned short* bfrag   = (unsigned short*)ws;                 // 1 MiB
    float*          cnorm   = (float*)(ws + (1u << 20));           // 4 KiB
    float*          xsq_part= (float*)(ws + (1u << 20) + 4096);    // 1 KiB
    float*          rowmax  = (float*)(ws + (1u << 20) + 8192);    // 512 KiB

    prep_bfrag_k<<<256, 256, 0, stream>>>(cb, bfrag);
    prep_cnorm_k<<<KCODES, 64, 0, stream>>>(cb, cnorm);
    xsq_k<<<256, 256, 0, stream>>>(x, xsq_part);
    vq_main_k<<<dim3(MROWS / BMROWS, NHALF), 256, 0, stream>>>(x, bfrag, cnorm, rowmax);
    finalize_k<<<1, 1024, 0, stream>>>(rowmax, xsq_part, out);
}

// Round 4
// 161.495 us; speedup vs baseline: 1.6830x; 1.6830x over previous
//
#include <hip/hip_runtime.h>

// Problem constants
#define BDIM   16
#define PDIM   12
#define TDIM   4096
#define WINW   41
#define PADW   20
#define DDIM   492      // P*WIN
#define DPAD   512      // padded K for MFMA (zeros beyond 492)
#define KCODES 1024
#define KSTEPS 16       // 512 / 32
#define NTILES 64       // 1024 / 16

#define WAVES      4                 // 256-thread blocks
#define ROWS_WAVE  32                // 2 slabs of 16 rows
#define BMROWS     (WAVES * ROWS_WAVE)    // 128 rows per block
#define NHALF      2                 // code-range split across blockIdx.y
#define NT_HALF    (NTILES / NHALF)  // 32 ntiles per sweep
#define NT_BYTES   (KSTEPS * 64 * 16)     // 16384 bytes per ntile
#define CHUNK_NT   2                 // ntiles per staged chunk
#define NCHUNK     (NT_HALF / CHUNK_NT)   // 16 chunks per sweep
#define CHUNK_BYTES (CHUNK_NT * NT_BYTES) // 32768

#define MROWS      (BDIM * TDIM)     // 65536

typedef __attribute__((ext_vector_type(8))) short  short8;  // 8 x bf16 (4 VGPRs)
typedef __attribute__((ext_vector_type(4))) float  f32x4;   // MFMA acc

__device__ __forceinline__ unsigned short f2bf(float f) {
    union { float f; unsigned int u; } v; v.f = f;
    unsigned int r = v.u + 0x7FFFu + ((v.u >> 16) & 1u);  // round-to-nearest-even
    return (unsigned short)(r >> 16);
}

// Pre-format codebook into B-fragment order for mfma_f32_16x16x32_bf16.
// frag idx = (nt*16 + ks)*64 + lane, 8 bf16 each:
//   B[k][n], n = nt*16 + (lane&15), k = ks*32 + (lane>>4)*8 + j
__global__ __launch_bounds__(256) void prep_bfrag_k(const float* __restrict__ cb,
                                                    unsigned short* __restrict__ bfrag) {
    int idx  = blockIdx.x * 256 + threadIdx.x;   // 0 .. 65535
    int lane = idx & 63;
    int ks   = (idx >> 6) & 15;
    int nt   = idx >> 10;
    int n    = nt * 16 + (lane & 15);
    int hi   = lane >> 4;
    short8 sv;
#pragma unroll
    for (int j = 0; j < 8; ++j) {
        int k = ks * 32 + hi * 8 + j;
        float f = (k < DDIM) ? cb[n * DDIM + k] : 0.f;
        sv[j] = (short)f2bf(f);
    }
    *(short8*)(bfrag + (size_t)idx * 8) = sv;
}

__global__ __launch_bounds__(64) void prep_cnorm_k(const float* __restrict__ cb,
                                                   float* __restrict__ cnorm) {
    int n = blockIdx.x;
    int lane = threadIdx.x;
    float s = 0.f;
    for (int d = lane; d < DDIM; d += 64) { float c = cb[n * DDIM + d]; s += c * c; }
#pragma unroll
    for (int m = 1; m < 64; m <<= 1) s += __shfl_xor(s, m, 64);
    if (lane == 0) cnorm[n] = s;
}

// Exact sum of ||f||^2 over all rows, via window multiplicity:
// mult(tt) = 41 - max(0,20-tt) - max(0,tt-4075). Per-block f32 partials.
__global__ __launch_bounds__(256) void xsq_k(const float* __restrict__ x,
                                             float* __restrict__ xsq_part) {
    float s = 0.f;
    for (int i = blockIdx.x * 256 + threadIdx.x; i < BDIM * PDIM * TDIM; i += 256 * 256) {
        int tt = i & (TDIM - 1);
        int mult = WINW - max(0, PADW - tt) - max(0, tt - (TDIM - 1 - PADW));
        float v = x[i];
        s += (float)mult * v * v;
    }
#pragma unroll
    for (int m = 1; m < 64; m <<= 1) s += __shfl_xor(s, m, 64);
    __shared__ float sm[4];
    if ((threadIdx.x & 63) == 0) sm[threadIdx.x >> 6] = s;
    __syncthreads();
    if (threadIdx.x == 0) xsq_part[blockIdx.x] = sm[0] + sm[1] + sm[2] + sm[3];
}

// Stage one 32 KiB chunk (2 ntiles) of bfrag into LDS (async, width 16, linear).
__device__ __forceinline__ void stage_chunk(const unsigned short* __restrict__ bfrag,
                                            unsigned char* smem_buf, int chunk,
                                            int wave, int lane) {
    const unsigned char* gsrc = (const unsigned char*)bfrag + (size_t)chunk * CHUNK_BYTES;
#pragma unroll
    for (int it = 0; it < 8; ++it) {
        int off = it * 4096 + wave * 1024;
        __builtin_amdgcn_global_load_lds(
            (const __attribute__((address_space(1))) unsigned int*)(gsrc + off + lane * 16),
            (__attribute__((address_space(3))) unsigned int*)(smem_buf + off),
            16, 0, 0);
    }
}

// Main sweep: block = 4 waves x 32 rows = 128 rows; blockIdx.y picks a
// 512-code half. Track per-row MAX score s = f.c - 0.5*||c||^2 only
// (dist = ||f||^2 - 2*smax). Row maxes -> ws.
// NOTE: no min-waves in launch_bounds — forcing 3 waves/EU (R3) made the
// allocator spill afr[] to scratch (235 MB of scratch writes, VGPR=84).
// Budget: afr 128 + bq 32 + acc 8 + addr ~= 185 VGPR -> 2 waves/SIMD,
// LDS 64 KiB -> 2 blocks/CU for cross-block barrier overlap.
__global__ __launch_bounds__(256) void vq_main_k(const float* __restrict__ x,
                                                 const unsigned short* __restrict__ bfrag,
                                                 const float* __restrict__ cnorm,
                                                 float* __restrict__ rowmax) {
    __shared__ unsigned char smem[2][CHUNK_BYTES];

    const int lane = threadIdx.x & 63;
    const int wave = threadIdx.x >> 6;
    const int ld   = lane & 15;
    const int hi   = lane >> 4;
    const int by   = blockIdx.y;
    const int chunk0 = by * NCHUNK;        // global chunk index base for this half
    const int rowbase = blockIdx.x * BMROWS + wave * ROWS_WAVE;

    // Kick off staging of first chunk; A-build overlaps the load latency.
    stage_chunk(bfrag, smem[0], chunk0, wave, lane);

    // ---- Build A fragments for 2 slabs (row = rowbase + s*16 + ld) ----
    short8 afr[2][KSTEPS];
#pragma unroll
    for (int s = 0; s < 2; ++s) {
        int m = rowbase + s * 16 + ld;
        int b = m >> 12;            // / TDIM
        int t = m & (TDIM - 1);
        const float* xb = x + (size_t)b * (PDIM * TDIM);
#pragma unroll
        for (int ks = 0; ks < KSTEPS; ++ks) {
            short8 a;
#pragma unroll
            for (int j = 0; j < 8; ++j) {
                int d = ks * 32 + hi * 8 + j;
                float v = 0.f;
                if (d < DDIM) {
                    int p  = d / WINW;
                    int w  = d - p * WINW;
                    int tt = t + w - PADW;
                    if (tt >= 0 && tt < TDIM) v = xb[p * TDIM + tt];
                }
                a[j] = (short)f2bf(v);
            }
            afr[s][ks] = a;
        }
    }

    float bs[2][4];
#pragma unroll
    for (int s = 0; s < 2; ++s)
#pragma unroll
        for (int r = 0; r < 4; ++r) bs[s][r] = -3.0e38f;

    __syncthreads();   // chunk 0 resident (barrier drains vmcnt)

    // ---- Sweep this half's 32 ntiles: 16 chunks x 2 ntiles ----
    for (int c = 0; c < NCHUNK; ++c) {
        if (c + 1 < NCHUNK) stage_chunk(bfrag, smem[(c + 1) & 1], chunk0 + c + 1, wave, lane);
        const unsigned char* cur = smem[c & 1];
#pragma unroll
        for (int ntl = 0; ntl < CHUNK_NT; ++ntl) {
            const int nt = (chunk0 + c) * CHUNK_NT + ntl;
            f32x4 acc0 = {0.f, 0.f, 0.f, 0.f};
            f32x4 acc1 = {0.f, 0.f, 0.f, 0.f};
            const short8* bp = (const short8*)(cur + ntl * NT_BYTES) + lane;
            // Two phases of {load 8 B-frags to regs, 16 MFMAs} — deep
            // lgkmcnt pipeline instead of 1-deep read->MFMA chains.
#pragma unroll
            for (int ph = 0; ph < 2; ++ph) {
                short8 bq[8];
#pragma unroll
                for (int i = 0; i < 8; ++i) bq[i] = bp[(ph * 8 + i) * 64];
#pragma unroll
                for (int i = 0; i < 8; ++i) {
                    acc0 = __builtin_amdgcn_mfma_f32_16x16x32_bf16(afr[0][ph * 8 + i], bq[i], acc0, 0, 0, 0);
                    acc1 = __builtin_amdgcn_mfma_f32_16x16x32_bf16(afr[1][ph * 8 + i], bq[i], acc1, 0, 0, 0);
                }
            }
            const float sb = -0.5f * cnorm[nt * 16 + ld];
#pragma unroll
            for (int r = 0; r < 4; ++r) {           // D: col(N)=lane&15, row(M)=hi*4+r
                bs[0][r] = fmaxf(bs[0][r], acc0[r] + sb);
                bs[1][r] = fmaxf(bs[1][r], acc1[r] + sb);
            }
        }
        __syncthreads();   // staging of c+1 done; all waves done reading cur
    }

    // ---- Max across the 16 lanes of each group (masks stay in-group) ----
#pragma unroll
    for (int msk = 1; msk < 16; msk <<= 1) {
#pragma unroll
        for (int s = 0; s < 2; ++s)
#pragma unroll
            for (int r = 0; r < 4; ++r)
                bs[s][r] = fmaxf(bs[s][r], __shfl_xor(bs[s][r], msk, 64));
    }

    // Lane ld==0 of each 16-lane group owns rows [rowbase + s*16 + hi*4 .. +3]
    if (ld == 0) {
        float* dst = rowmax + (size_t)by * MROWS + rowbase + hi * 4;
#pragma unroll
        for (int s = 0; s < 2; ++s) {
            float4 v = make_float4(bs[s][0], bs[s][1], bs[s][2], bs[s][3]);
            *(float4*)(dst + s * 16) = v;
        }
    }
}

// loss = 0.25 * (Sxx - 2*sum_rows max_half(rowmax)) / (65536*492)
__global__ __launch_bounds__(1024) void finalize_k(const float* __restrict__ rowmax,
                                                   const float* __restrict__ xsq_part,
                                                   float* __restrict__ out) {
    __shared__ double sm[1024];
    float s = 0.f;
    for (int r = threadIdx.x; r < MROWS; r += 1024)
        s += fmaxf(rowmax[r], rowmax[MROWS + r]);
    sm[threadIdx.x] = (double)s;
    __syncthreads();
    for (int st = 512; st > 0; st >>= 1) {
        if ((int)threadIdx.x < st) sm[threadIdx.x] += sm[threadIdx.x + st];
        __syncthreads();
    }
    if (threadIdx.x == 0) {
        double sxx = 0.0;
        for (int i = 0; i < 256; ++i) sxx += (double)xsq_part[i];
        double sdist = sxx - 2.0 * sm[0];
        out[0] = (float)(0.25 * sdist / ((double)MROWS * (double)DDIM));
    }
}

extern "C" void kernel_launch(void* const* d_in, const int* in_sizes, int n_in,
                              void* d_out, int out_size, void* d_ws, size_t ws_size,
                              hipStream_t stream) {
    const float* x  = (const float*)d_in[0];   // (16,12,4096) f32
    const float* cb = (const float*)d_in[1];   // (1024,492) f32
    float* out = (float*)d_out;

    // workspace layout (~1.55 MiB)
    char* ws = (char*)d_ws;
    unsigned short* bfrag   = (unsigned short*)ws;                 // 1 MiB
    float*          cnorm   = (float*)(ws + (1u << 20));           // 4 KiB
    float*          xsq_part= (float*)(ws + (1u << 20) + 4096);    // 1 KiB
    float*          rowmax  = (float*)(ws + (1u << 20) + 8192);    // 512 KiB

    prep_bfrag_k<<<256, 256, 0, stream>>>(cb, bfrag);
    prep_cnorm_k<<<KCODES, 64, 0, stream>>>(cb, cnorm);
    xsq_k<<<256, 256, 0, stream>>>(x, xsq_part);
    vq_main_k<<<dim3(MROWS / BMROWS, NHALF), 256, 0, stream>>>(x, bfrag, cnorm, rowmax);
    finalize_k<<<1, 1024, 0, stream>>>(rowmax, xsq_part, out);
}

// Round 5
// 116.380 us; speedup vs baseline: 2.3355x; 1.3877x over previous
//
#include <hip/hip_runtime.h>

// Problem constants
#define BDIM   16
#define PDIM   12
#define TDIM   4096
#define WINW   41
#define PADW   20
#define DDIM   492      // P*WIN
#define DPAD   512      // padded K (zeros beyond 492)
#define KCODES 1024

// fp8 32x32x16 MFMA geometry
#define KS32   32                   // K-steps of 16 -> 512
#define NT32   32                   // code tiles of 32 -> 1024
#define NT32_BYTES (KS32 * 64 * 8)  // 16 KiB per code tile

#define WAVES      4
#define ROWS_WAVE  32
#define BMROWS     (WAVES * ROWS_WAVE)   // 128 rows per block
#define MROWS      (BDIM * TDIM)         // 65536
#define NBLK       (MROWS / BMROWS)      // 512 (= 2 blocks/CU, all resident)

typedef __attribute__((ext_vector_type(16))) float f32x16;

// two f32 pairs -> 4 e4m3 bytes (RNE, saturating) via v_cvt_pk_fp8_f32
__device__ __forceinline__ unsigned int pack4_fp8(float a, float b, float c, float d) {
    int v = 0;
    v = __builtin_amdgcn_cvt_pk_fp8_f32(a, b, v, false);  // bytes 0,1
    v = __builtin_amdgcn_cvt_pk_fp8_f32(c, d, v, true);   // bytes 2,3
    return (unsigned int)v;
}

// Pre-format codebook into fp8 B-fragments for mfma_f32_32x32x16_fp8_fp8.
// frag idx = (nt*KS32 + ks)*64 + lane, 8 bytes each:
//   B[k][n], n = nt*32 + (lane&31), k = ks*16 + (lane>>5)*8 + j  (byte j)
__global__ __launch_bounds__(256) void prep_bfrag_k(const float* __restrict__ cb,
                                                    unsigned long long* __restrict__ bfrag) {
    int idx  = blockIdx.x * 256 + threadIdx.x;   // 0..65535
    int lane = idx & 63;
    int ks   = (idx >> 6) & (KS32 - 1);
    int nt   = idx >> 11;
    int n    = nt * 32 + (lane & 31);
    int hi2  = lane >> 5;
    float v[8];
#pragma unroll
    for (int j = 0; j < 8; ++j) {
        int k = ks * 16 + hi2 * 8 + j;
        v[j] = (k < DDIM) ? cb[n * DDIM + k] : 0.f;
    }
    unsigned int lo = pack4_fp8(v[0], v[1], v[2], v[3]);
    unsigned int hi = pack4_fp8(v[4], v[5], v[6], v[7]);
    bfrag[idx] = ((unsigned long long)hi << 32) | lo;
}

// Exact fp32 code norms.
__global__ __launch_bounds__(64) void prep_cnorm_k(const float* __restrict__ cb,
                                                   float* __restrict__ cnorm) {
    int n = blockIdx.x;
    int lane = threadIdx.x;
    float s = 0.f;
    for (int d = lane; d < DDIM; d += 64) { float c = cb[n * DDIM + d]; s += c * c; }
#pragma unroll
    for (int m = 1; m < 64; m <<= 1) s += __shfl_xor(s, m, 64);
    if (lane == 0) cnorm[n] = s;
}

// Exact sum of ||f||^2 over all rows via window multiplicity:
// mult(tt) = 41 - max(0,20-tt) - max(0,tt-4075).
__global__ __launch_bounds__(256) void xsq_k(const float* __restrict__ x,
                                             float* __restrict__ xsq_part) {
    float s = 0.f;
    for (int i = blockIdx.x * 256 + threadIdx.x; i < BDIM * PDIM * TDIM; i += 256 * 256) {
        int tt = i & (TDIM - 1);
        int mult = WINW - max(0, PADW - tt) - max(0, tt - (TDIM - 1 - PADW));
        float v = x[i];
        s += (float)mult * v * v;
    }
#pragma unroll
    for (int m = 1; m < 64; m <<= 1) s += __shfl_xor(s, m, 64);
    __shared__ float sm[4];
    if ((threadIdx.x & 63) == 0) sm[threadIdx.x >> 6] = s;
    __syncthreads();
    if (threadIdx.x == 0) xsq_part[blockIdx.x] = sm[0] + sm[1] + sm[2] + sm[3];
}

// Stage one 16 KiB code tile into LDS (async, width 16, linear order).
__device__ __forceinline__ void stage_nt(const unsigned char* __restrict__ bfrag,
                                         unsigned char* dst, int nt, int wave, int lane) {
    const unsigned char* g = bfrag + (size_t)nt * NT32_BYTES;
#pragma unroll
    for (int it = 0; it < 4; ++it) {
        int off = it * 4096 + wave * 1024;
        __builtin_amdgcn_global_load_lds(
            (const __attribute__((address_space(1))) unsigned int*)(g + off + lane * 16),
            (__attribute__((address_space(3))) unsigned int*)(dst + off),
            16, 0, 0);
    }
}

// Main sweep: 512 blocks x 4 waves x 32 rows. Each wave keeps its 32-row
// fp8 A-slab (64 VGPR) in registers; all 1024 codes swept per block through
// double-buffered 16 KiB LDS tiles. Track per-row MAX score
// s = f.c - 0.5*||c||^2 (dist = ||f||^2 - 2*smax); block-local row-max sum.
__global__ __launch_bounds__(256) void vq_main_k(const float* __restrict__ x,
                                                 const unsigned char* __restrict__ bfrag,
                                                 const float* __restrict__ cnorm,
                                                 float* __restrict__ bpart) {
    __shared__ __align__(16) unsigned char smem[2][NT32_BYTES];
    __shared__ float gsum[2 * WAVES];

    const int lane = threadIdx.x & 63;
    const int wave = threadIdx.x >> 6;
    const int col  = lane & 31;     // B/D column within tile
    const int hi2  = lane >> 5;
    const int rowbase = blockIdx.x * BMROWS + wave * ROWS_WAVE;

    stage_nt(bfrag, smem[0], 0, wave, lane);

    // ---- Build fp8 A-slab: row = rowbase + col, k = ks*16 + hi2*8 + j ----
    long afr[KS32];
    {
        int row = rowbase + col;
        int b = row >> 12;
        int t = row & (TDIM - 1);
        const float* xb = x + (size_t)b * (PDIM * TDIM);
#pragma unroll
        for (int ks = 0; ks < KS32; ++ks) {
            float v[8];
#pragma unroll
            for (int j = 0; j < 8; ++j) {
                int d = ks * 16 + hi2 * 8 + j;
                float f = 0.f;
                if (d < DDIM) {
                    int p  = d / WINW;
                    int w  = d - p * WINW;
                    int tt = t + w - PADW;
                    if (tt >= 0 && tt < TDIM) f = xb[p * TDIM + tt];
                }
                v[j] = f;
            }
            unsigned int lo = pack4_fp8(v[0], v[1], v[2], v[3]);
            unsigned int hi = pack4_fp8(v[4], v[5], v[6], v[7]);
            afr[ks] = (long)(((unsigned long long)hi << 32) | lo);
        }
    }

    f32x16 bs;
#pragma unroll
    for (int r = 0; r < 16; ++r) bs[r] = -3.0e38f;

    __syncthreads();   // tile 0 resident

    for (int c = 0; c < NT32; ++c) {
        if (c + 1 < NT32) stage_nt(bfrag, smem[(c + 1) & 1], c + 1, wave, lane);
        const float sb = -0.5f * cnorm[c * 32 + col];
        const long* bp = (const long*)smem[c & 1] + lane;
        f32x16 accA, accB;
#pragma unroll
        for (int r = 0; r < 16; ++r) { accA[r] = 0.f; accB[r] = 0.f; }
        // 8 phases of {4 ds_read_b64, 4 MFMA}; two independent acc chains
#pragma unroll
        for (int ph = 0; ph < 8; ++ph) {
            long b0 = bp[(ph * 4 + 0) * 64];
            long b1 = bp[(ph * 4 + 1) * 64];
            long b2 = bp[(ph * 4 + 2) * 64];
            long b3 = bp[(ph * 4 + 3) * 64];
            accA = __builtin_amdgcn_mfma_f32_32x32x16_fp8_fp8(afr[ph * 4 + 0], b0, accA, 0, 0, 0);
            accB = __builtin_amdgcn_mfma_f32_32x32x16_fp8_fp8(afr[ph * 4 + 1], b1, accB, 0, 0, 0);
            accA = __builtin_amdgcn_mfma_f32_32x32x16_fp8_fp8(afr[ph * 4 + 2], b2, accA, 0, 0, 0);
            accB = __builtin_amdgcn_mfma_f32_32x32x16_fp8_fp8(afr[ph * 4 + 3], b3, accB, 0, 0, 0);
        }
#pragma unroll
        for (int r = 0; r < 16; ++r) bs[r] = fmaxf(bs[r], accA[r] + accB[r] + sb);
        __syncthreads();   // staging of c+1 done; all waves done with cur
    }

    // ---- Per-row max across the 32 col-lanes (masks<32 preserve hi2) ----
#pragma unroll
    for (int m = 1; m < 32; m <<= 1)
#pragma unroll
        for (int r = 0; r < 16; ++r)
            bs[r] = fmaxf(bs[r], __shfl_xor(bs[r], m, 64));

    // D rows: row = (r&3) + 8*(r>>2) + 4*hi2 — bijective over 32 rows per
    // (hi2, r); sum over all rows is mapping-invariant.
    if (col == 0) {
        float s = 0.f;
#pragma unroll
        for (int r = 0; r < 16; ++r) s += bs[r];
        gsum[wave * 2 + hi2] = s;
    }
    __syncthreads();
    if (threadIdx.x == 0) {
        float tot = 0.f;
#pragma unroll
        for (int i = 0; i < 2 * WAVES; ++i) tot += gsum[i];
        bpart[blockIdx.x] = tot;
    }
}

// loss = 0.25 * (Sxx - 2*sum_blocks bpart) / (65536*492)
__global__ __launch_bounds__(256) void finalize_k(const float* __restrict__ bpart,
                                                  const float* __restrict__ xsq_part,
                                                  float* __restrict__ out) {
    __shared__ double sm[256];
    int tid = threadIdx.x;
    sm[tid] = (double)bpart[tid] + (double)bpart[tid + 256];
    __syncthreads();
    for (int st = 128; st > 0; st >>= 1) {
        if (tid < st) sm[tid] += sm[tid + st];
        __syncthreads();
    }
    double S1 = sm[0];
    __syncthreads();
    sm[tid] = (double)xsq_part[tid];
    __syncthreads();
    for (int st = 128; st > 0; st >>= 1) {
        if (tid < st) sm[tid] += sm[tid + st];
        __syncthreads();
    }
    if (tid == 0)
        out[0] = (float)(0.25 * (sm[0] - 2.0 * S1) / ((double)MROWS * (double)DDIM));
}

extern "C" void kernel_launch(void* const* d_in, const int* in_sizes, int n_in,
                              void* d_out, int out_size, void* d_ws, size_t ws_size,
                              hipStream_t stream) {
    const float* x  = (const float*)d_in[0];   // (16,12,4096) f32
    const float* cb = (const float*)d_in[1];   // (1024,492) f32
    float* out = (float*)d_out;

    // workspace layout (~524 KiB)
    char* ws = (char*)d_ws;
    unsigned long long* bfrag = (unsigned long long*)ws;            // 512 KiB
    float* cnorm    = (float*)(ws + (512u << 10));                  // 4 KiB
    float* xsq_part = (float*)(ws + (512u << 10) + 4096);           // 1 KiB
    float* bpart    = (float*)(ws + (512u << 10) + 8192);           // 2 KiB

    prep_bfrag_k<<<256, 256, 0, stream>>>(cb, bfrag);
    prep_cnorm_k<<<KCODES, 64, 0, stream>>>(cb, cnorm);
    xsq_k<<<256, 256, 0, stream>>>(x, xsq_part);
    vq_main_k<<<NBLK, 256, 0, stream>>>(x, (const unsigned char*)bfrag, cnorm, bpart);
    finalize_k<<<1, 256, 0, stream>>>(bpart, xsq_part, out);
}

// Round 6
// 114.091 us; speedup vs baseline: 2.3823x; 1.0201x over previous
//
#include <hip/hip_runtime.h>

// Problem constants
#define BDIM   16
#define PDIM   12
#define TDIM   4096
#define WINW   41
#define PADW   20
#define DDIM   492      // P*WIN
#define KCODES 1024

// fp8 32x32x16 MFMA geometry
#define KS32   32                   // K-steps of 16 -> 512
#define NT32   32                   // code tiles of 32 -> 1024
#define NT32_BYTES (KS32 * 64 * 8)  // 16 KiB per code tile

#define WAVES      4
#define ROWS_WAVE  32
#define BMROWS     (WAVES * ROWS_WAVE)   // 128 rows per block
#define MROWS      (BDIM * TDIM)         // 65536
#define NBLK       (MROWS / BMROWS)      // 512 (= 2 blocks/CU, all resident)

typedef __attribute__((ext_vector_type(16))) float f32x16;

// two f32 pairs -> 4 e4m3 bytes (RNE, saturating) via v_cvt_pk_fp8_f32
__device__ __forceinline__ unsigned int pack4_fp8(float a, float b, float c, float d) {
    int v = 0;
    v = __builtin_amdgcn_cvt_pk_fp8_f32(a, b, v, false);  // bytes 0,1
    v = __builtin_amdgcn_cvt_pk_fp8_f32(c, d, v, true);   // bytes 2,3
    return (unsigned int)v;
}

// Pre-format codebook into fp8 B-fragments for mfma_f32_32x32x16_fp8_fp8.
// frag idx = (nt*KS32 + ks)*64 + lane, 8 bytes each:
//   B[k][n], n = nt*32 + (lane&31), k = ks*16 + (lane>>5)*8 + j  (byte j)
__global__ __launch_bounds__(256) void prep_bfrag_k(const float* __restrict__ cb,
                                                    unsigned long long* __restrict__ bfrag) {
    int idx  = blockIdx.x * 256 + threadIdx.x;   // 0..65535
    int lane = idx & 63;
    int ks   = (idx >> 6) & (KS32 - 1);
    int nt   = idx >> 11;
    int n    = nt * 32 + (lane & 31);
    int hi2  = lane >> 5;
    float v[8];
#pragma unroll
    for (int j = 0; j < 8; ++j) {
        int k = ks * 16 + hi2 * 8 + j;
        v[j] = (k < DDIM) ? cb[n * DDIM + k] : 0.f;
    }
    unsigned int lo = pack4_fp8(v[0], v[1], v[2], v[3]);
    unsigned int hi = pack4_fp8(v[4], v[5], v[6], v[7]);
    bfrag[idx] = ((unsigned long long)hi << 32) | lo;
}

// Exact fp32 code norms.
__global__ __launch_bounds__(64) void prep_cnorm_k(const float* __restrict__ cb,
                                                   float* __restrict__ cnorm) {
    int n = blockIdx.x;
    int lane = threadIdx.x;
    float s = 0.f;
    for (int d = lane; d < DDIM; d += 64) { float c = cb[n * DDIM + d]; s += c * c; }
#pragma unroll
    for (int m = 1; m < 64; m <<= 1) s += __shfl_xor(s, m, 64);
    if (lane == 0) cnorm[n] = s;
}

// Exact sum of ||f||^2 over all rows via window multiplicity:
// mult(tt) = 41 - max(0,20-tt) - max(0,tt-4075).
__global__ __launch_bounds__(256) void xsq_k(const float* __restrict__ x,
                                             float* __restrict__ xsq_part) {
    float s = 0.f;
    for (int i = blockIdx.x * 256 + threadIdx.x; i < BDIM * PDIM * TDIM; i += 256 * 256) {
        int tt = i & (TDIM - 1);
        int mult = WINW - max(0, PADW - tt) - max(0, tt - (TDIM - 1 - PADW));
        float v = x[i];
        s += (float)mult * v * v;
    }
#pragma unroll
    for (int m = 1; m < 64; m <<= 1) s += __shfl_xor(s, m, 64);
    __shared__ float sm[4];
    if ((threadIdx.x & 63) == 0) sm[threadIdx.x >> 6] = s;
    __syncthreads();
    if (threadIdx.x == 0) xsq_part[blockIdx.x] = sm[0] + sm[1] + sm[2] + sm[3];
}

// Stage one 16 KiB code tile into LDS (async, width 16, linear order).
__device__ __forceinline__ void stage_nt(const unsigned char* __restrict__ bfrag,
                                         unsigned char* dst, int nt, int wave, int lane) {
    const unsigned char* g = bfrag + (size_t)nt * NT32_BYTES;
#pragma unroll
    for (int it = 0; it < 4; ++it) {
        int off = it * 4096 + wave * 1024;
        __builtin_amdgcn_global_load_lds(
            (const __attribute__((address_space(1))) unsigned int*)(g + off + lane * 16),
            (__attribute__((address_space(3))) unsigned int*)(dst + off),
            16, 0, 0);
    }
}

// Main sweep: 512 blocks x 4 waves x 32 rows; fp8 A-slab in registers;
// codes streamed through TRIPLE-buffered 16 KiB LDS tiles with depth-2
// prefetch and counted vmcnt (never 0 in the loop) + raw s_barrier —
// staging stays in flight across barriers (T3/T4). Steady-state loop has
// NO vmem ops except the 4 stage loads, so vmcnt(4) accounting is exact
// (cnorm bias comes from an LDS table).
__global__ __launch_bounds__(256) void vq_main_k(const float* __restrict__ x,
                                                 const unsigned char* __restrict__ bfrag,
                                                 const float* __restrict__ cnorm,
                                                 float* __restrict__ bpart) {
    __shared__ __align__(16) unsigned char smem[3][NT32_BYTES];
    __shared__ float sb_lds[KCODES];
    __shared__ float gsum[2 * WAVES];

    const int lane = threadIdx.x & 63;
    const int wave = threadIdx.x >> 6;
    const int col  = lane & 31;     // B/D column within tile
    const int hi2  = lane >> 5;
    const int rowbase = blockIdx.x * BMROWS + wave * ROWS_WAVE;

    // Depth-2 staging kickoff; latency covered by sb-table + A-build below.
    stage_nt(bfrag, smem[0], 0, wave, lane);
    stage_nt(bfrag, smem[1], 1, wave, lane);

    // Bias table: sb_lds[n] = -0.5*||c_n||^2 (4 KiB LDS)
    for (int i = threadIdx.x; i < KCODES; i += 256)
        sb_lds[i] = -0.5f * cnorm[i];

    // ---- Build fp8 A-slab: row = rowbase + col, k = ks*16 + hi2*8 + j ----
    long afr[KS32];
    {
        int row = rowbase + col;
        int b = row >> 12;
        int t = row & (TDIM - 1);
        const float* xb = x + (size_t)b * (PDIM * TDIM);
#pragma unroll
        for (int ks = 0; ks < KS32; ++ks) {
            float v[8];
#pragma unroll
            for (int j = 0; j < 8; ++j) {
                int d = ks * 16 + hi2 * 8 + j;
                float f = 0.f;
                if (d < DDIM) {
                    int p  = d / WINW;
                    int w  = d - p * WINW;
                    int tt = t + w - PADW;
                    if (tt >= 0 && tt < TDIM) f = xb[p * TDIM + tt];
                }
                v[j] = f;
            }
            unsigned int lo = pack4_fp8(v[0], v[1], v[2], v[3]);
            unsigned int hi = pack4_fp8(v[4], v[5], v[6], v[7]);
            afr[ks] = (long)(((unsigned long long)hi << 32) | lo);
        }
    }

    f32x16 bs;
#pragma unroll
    for (int r = 0; r < 16; ++r) bs[r] = -3.0e38f;

    // One full drain at pipeline entry (tiles 0,1 resident; sb_lds visible).
    __syncthreads();

    for (int c = 0; c < NT32; ++c) {
        if (c > 0) {
            // stage(c) retired (only stage(c+1)'s 4 loads may remain in flight)
            asm volatile("s_waitcnt vmcnt(4)" ::: "memory");
            __builtin_amdgcn_s_barrier();   // all waves: tile c complete in LDS;
                                            // all waves done reading buf[(c-1)%3]
            __builtin_amdgcn_sched_barrier(0);
        }
        // Prefetch tile c+2 into the buffer freed at c-1 (or never used, c=0).
        if (c + 2 < NT32) stage_nt(bfrag, smem[(c + 2) % 3], c + 2, wave, lane);

        const long* bp = (const long*)(smem[c % 3]) + lane;
        f32x16 accA, accB;
#pragma unroll
        for (int r = 0; r < 16; ++r) { accA[r] = 0.f; accB[r] = 0.f; }

        __builtin_amdgcn_s_setprio(1);
#pragma unroll
        for (int ph = 0; ph < 8; ++ph) {
            long b0 = bp[(ph * 4 + 0) * 64];
            long b1 = bp[(ph * 4 + 1) * 64];
            long b2 = bp[(ph * 4 + 2) * 64];
            long b3 = bp[(ph * 4 + 3) * 64];
            accA = __builtin_amdgcn_mfma_f32_32x32x16_fp8_fp8(afr[ph * 4 + 0], b0, accA, 0, 0, 0);
            accB = __builtin_amdgcn_mfma_f32_32x32x16_fp8_fp8(afr[ph * 4 + 1], b1, accB, 0, 0, 0);
            accA = __builtin_amdgcn_mfma_f32_32x32x16_fp8_fp8(afr[ph * 4 + 2], b2, accA, 0, 0, 0);
            accB = __builtin_amdgcn_mfma_f32_32x32x16_fp8_fp8(afr[ph * 4 + 3], b3, accB, 0, 0, 0);
        }
        __builtin_amdgcn_s_setprio(0);

        const float sb = sb_lds[c * 32 + col];   // ds_read (lgkmcnt, not vmcnt)
#pragma unroll
        for (int r = 0; r < 16; ++r) bs[r] = fmaxf(bs[r], accA[r] + accB[r] + sb);
    }

    // ---- Per-row max across the 32 col-lanes (masks<32 preserve hi2) ----
#pragma unroll
    for (int m = 1; m < 32; m <<= 1)
#pragma unroll
        for (int r = 0; r < 16; ++r)
            bs[r] = fmaxf(bs[r], __shfl_xor(bs[r], m, 64));

    // D rows: row = (r&3) + 8*(r>>2) + 4*hi2 — bijective over 32 rows per
    // (hi2, r); sum over all rows is mapping-invariant.
    if (col == 0) {
        float s = 0.f;
#pragma unroll
        for (int r = 0; r < 16; ++r) s += bs[r];
        gsum[wave * 2 + hi2] = s;
    }
    __syncthreads();
    if (threadIdx.x == 0) {
        float tot = 0.f;
#pragma unroll
        for (int i = 0; i < 2 * WAVES; ++i) tot += gsum[i];
        bpart[blockIdx.x] = tot;
    }
}

// loss = 0.25 * (Sxx - 2*sum_blocks bpart) / (65536*492)
__global__ __launch_bounds__(256) void finalize_k(const float* __restrict__ bpart,
                                                  const float* __restrict__ xsq_part,
                                                  float* __restrict__ out) {
    __shared__ double sm[256];
    int tid = threadIdx.x;
    sm[tid] = (double)bpart[tid] + (double)bpart[tid + 256];
    __syncthreads();
    for (int st = 128; st > 0; st >>= 1) {
        if (tid < st) sm[tid] += sm[tid + st];
        __syncthreads();
    }
    double S1 = sm[0];
    __syncthreads();
    sm[tid] = (double)xsq_part[tid];
    __syncthreads();
    for (int st = 128; st > 0; st >>= 1) {
        if (tid < st) sm[tid] += sm[tid + st];
        __syncthreads();
    }
    if (tid == 0)
        out[0] = (float)(0.25 * (sm[0] - 2.0 * S1) / ((double)MROWS * (double)DDIM));
}

extern "C" void kernel_launch(void* const* d_in, const int* in_sizes, int n_in,
                              void* d_out, int out_size, void* d_ws, size_t ws_size,
                              hipStream_t stream) {
    const float* x  = (const float*)d_in[0];   // (16,12,4096) f32
    const float* cb = (const float*)d_in[1];   // (1024,492) f32
    float* out = (float*)d_out;

    // workspace layout (~524 KiB)
    char* ws = (char*)d_ws;
    unsigned long long* bfrag = (unsigned long long*)ws;            // 512 KiB
    float* cnorm    = (float*)(ws + (512u << 10));                  // 4 KiB
    float* xsq_part = (float*)(ws + (512u << 10) + 4096);           // 1 KiB
    float* bpart    = (float*)(ws + (512u << 10) + 8192);           // 2 KiB

    prep_bfrag_k<<<256, 256, 0, stream>>>(cb, bfrag);
    prep_cnorm_k<<<KCODES, 64, 0, stream>>>(cb, cnorm);
    xsq_k<<<256, 256, 0, stream>>>(x, xsq_part);
    vq_main_k<<<NBLK, 256, 0, stream>>>(x, (const unsigned char*)bfrag, cnorm, bpart);
    finalize_k<<<1, 256, 0, stream>>>(bpart, xsq_part, out);
}

// Round 7
// 92.959 us; speedup vs baseline: 2.9239x; 1.2273x over previous
//
#include <hip/hip_runtime.h>

// Problem constants
#define BDIM   16
#define PDIM   12
#define TDIM   4096
#define WINW   41
#define PADW   20
#define DDIM   492      // P*WIN
#define KCODES 1024

// fp8 32x32x16 MFMA geometry
#define KS32   32                   // K-steps of 16 -> 512
#define NT32   32                   // code tiles of 32 -> 1024
#define NT32_BYTES (KS32 * 64 * 8)  // 16 KiB per code tile

#define WAVES      8                 // 512-thread blocks
#define ROWS_WAVE  32
#define BMROWS     (WAVES * ROWS_WAVE)   // 256 rows per block
#define MROWS      (BDIM * TDIM)         // 65536
#define NBLK       (MROWS / BMROWS)      // 256 = exactly 1 block/CU, single round

typedef __attribute__((ext_vector_type(16))) float f32x16;

// two f32 pairs -> 4 e4m3 bytes (RNE, saturating) via v_cvt_pk_fp8_f32
__device__ __forceinline__ unsigned int pack4_fp8(float a, float b, float c, float d) {
    int v = 0;
    v = __builtin_amdgcn_cvt_pk_fp8_f32(a, b, v, false);  // bytes 0,1
    v = __builtin_amdgcn_cvt_pk_fp8_f32(c, d, v, true);   // bytes 2,3
    return (unsigned int)v;
}

// Pre-format codebook into fp8 B-fragments for mfma_f32_32x32x16_fp8_fp8.
// frag idx = (nt*KS32 + ks)*64 + lane, 8 bytes each:
//   B[k][n], n = nt*32 + (lane&31), k = ks*16 + (lane>>5)*8 + j  (byte j)
__global__ __launch_bounds__(256) void prep_bfrag_k(const float* __restrict__ cb,
                                                    unsigned long long* __restrict__ bfrag) {
    int idx  = blockIdx.x * 256 + threadIdx.x;   // 0..65535
    int lane = idx & 63;
    int ks   = (idx >> 6) & (KS32 - 1);
    int nt   = idx >> 11;
    int n    = nt * 32 + (lane & 31);
    int hi2  = lane >> 5;
    float v[8];
#pragma unroll
    for (int j = 0; j < 8; ++j) {
        int k = ks * 16 + hi2 * 8 + j;
        v[j] = (k < DDIM) ? cb[n * DDIM + k] : 0.f;
    }
    unsigned int lo = pack4_fp8(v[0], v[1], v[2], v[3]);
    unsigned int hi = pack4_fp8(v[4], v[5], v[6], v[7]);
    bfrag[idx] = ((unsigned long long)hi << 32) | lo;
}

// Exact fp32 code norms.
__global__ __launch_bounds__(64) void prep_cnorm_k(const float* __restrict__ cb,
                                                   float* __restrict__ cnorm) {
    int n = blockIdx.x;
    int lane = threadIdx.x;
    float s = 0.f;
    for (int d = lane; d < DDIM; d += 64) { float c = cb[n * DDIM + d]; s += c * c; }
#pragma unroll
    for (int m = 1; m < 64; m <<= 1) s += __shfl_xor(s, m, 64);
    if (lane == 0) cnorm[n] = s;
}

// Exact sum of ||f||^2 over all rows via window multiplicity:
// mult(tt) = 41 - max(0,20-tt) - max(0,tt-4075).
__global__ __launch_bounds__(256) void xsq_k(const float* __restrict__ x,
                                             float* __restrict__ xsq_part) {
    float s = 0.f;
    for (int i = blockIdx.x * 256 + threadIdx.x; i < BDIM * PDIM * TDIM; i += 256 * 256) {
        int tt = i & (TDIM - 1);
        int mult = WINW - max(0, PADW - tt) - max(0, tt - (TDIM - 1 - PADW));
        float v = x[i];
        s += (float)mult * v * v;
    }
#pragma unroll
    for (int m = 1; m < 64; m <<= 1) s += __shfl_xor(s, m, 64);
    __shared__ float sm[4];
    if ((threadIdx.x & 63) == 0) sm[threadIdx.x >> 6] = s;
    __syncthreads();
    if (threadIdx.x == 0) xsq_part[blockIdx.x] = sm[0] + sm[1] + sm[2] + sm[3];
}

// Stage one 16 KiB code tile into LDS (async, width 16, linear order).
// 8 waves x 2 calls x 64 lanes x 16 B = 16 KiB. => 2 vmcnt slots per stage/wave.
__device__ __forceinline__ void stage_nt(const unsigned char* __restrict__ bfrag,
                                         unsigned char* dst, int nt, int wave, int lane) {
    const unsigned char* g = bfrag + (size_t)nt * NT32_BYTES;
#pragma unroll
    for (int it = 0; it < 2; ++it) {
        int off = wave * 2048 + it * 1024;
        __builtin_amdgcn_global_load_lds(
            (const __attribute__((address_space(1))) unsigned int*)(g + off + lane * 16),
            (__attribute__((address_space(3))) unsigned int*)(dst + off),
            16, 0, 0);
    }
}

// Main sweep: 256 blocks (exactly 1/CU, whole grid co-resident, single round)
// x 8 waves x 32 rows. fp8 A-slab in registers; codes streamed through
// triple-buffered 16 KiB LDS tiles, depth-2 prefetch, counted vmcnt
// (vmcnt(2) steady state; vmcnt(0) only at the final tile) + raw s_barrier.
// 4 independent MFMA acc chains per wave (8/SIMD) cover MFMA dep latency.
__global__ __launch_bounds__(512) void vq_main_k(const float* __restrict__ x,
                                                 const unsigned char* __restrict__ bfrag,
                                                 const float* __restrict__ cnorm,
                                                 float* __restrict__ bpart) {
    __shared__ __align__(16) unsigned char smem[3][NT32_BYTES];
    __shared__ float sb_lds[KCODES];
    __shared__ float gsum[2 * WAVES];

    const int lane = threadIdx.x & 63;
    const int wave = threadIdx.x >> 6;
    const int col  = lane & 31;     // B/D column within tile
    const int hi2  = lane >> 5;
    const int rowbase = blockIdx.x * BMROWS + wave * ROWS_WAVE;

    // Depth-2 staging kickoff; latency covered by sb-table + A-build below.
    stage_nt(bfrag, smem[0], 0, wave, lane);
    stage_nt(bfrag, smem[1], 1, wave, lane);

    // Bias table: sb_lds[n] = -0.5*||c_n||^2 (4 KiB LDS)
    for (int i = threadIdx.x; i < KCODES; i += 512)
        sb_lds[i] = -0.5f * cnorm[i];

    // ---- Build fp8 A-slab: row = rowbase + col, k = ks*16 + hi2*8 + j ----
    long afr[KS32];
    {
        int row = rowbase + col;
        int b = row >> 12;
        int t = row & (TDIM - 1);
        const float* xb = x + (size_t)b * (PDIM * TDIM);
#pragma unroll
        for (int ks = 0; ks < KS32; ++ks) {
            float v[8];
#pragma unroll
            for (int j = 0; j < 8; ++j) {
                int d = ks * 16 + hi2 * 8 + j;
                float f = 0.f;
                if (d < DDIM) {
                    int p  = d / WINW;
                    int w  = d - p * WINW;
                    int tt = t + w - PADW;
                    if (tt >= 0 && tt < TDIM) f = xb[p * TDIM + tt];
                }
                v[j] = f;
            }
            unsigned int lo = pack4_fp8(v[0], v[1], v[2], v[3]);
            unsigned int hi = pack4_fp8(v[4], v[5], v[6], v[7]);
            afr[ks] = (long)(((unsigned long long)hi << 32) | lo);
        }
    }

    f32x16 bs;
#pragma unroll
    for (int r = 0; r < 16; ++r) bs[r] = -3.0e38f;

    // One full drain at pipeline entry (tiles 0,1 resident; sb_lds visible).
    __syncthreads();

    for (int c = 0; c < NT32; ++c) {
        if (c > 0) {
            if (c + 1 < NT32) {
                // stage(c+1)'s 2 loads may remain in flight; stage(c) retired
                asm volatile("s_waitcnt vmcnt(2)" ::: "memory");
            } else {
                // last tile: nothing should remain in flight (tail-safe)
                asm volatile("s_waitcnt vmcnt(0)" ::: "memory");
            }
            __builtin_amdgcn_s_barrier();   // tile c complete; buf[(c-1)%3] free
            __builtin_amdgcn_sched_barrier(0);
        }
        // Prefetch tile c+2 into the buffer freed at c-1.
        if (c + 2 < NT32) stage_nt(bfrag, smem[(c + 2) % 3], c + 2, wave, lane);

        const long* bp = (const long*)(smem[c % 3]) + lane;
        f32x16 accA, accB, accC, accD;
#pragma unroll
        for (int r = 0; r < 16; ++r) { accA[r] = 0.f; accB[r] = 0.f; accC[r] = 0.f; accD[r] = 0.f; }

        __builtin_amdgcn_s_setprio(1);
#pragma unroll
        for (int ph = 0; ph < 8; ++ph) {
            long b0 = bp[(ph * 4 + 0) * 64];
            long b1 = bp[(ph * 4 + 1) * 64];
            long b2 = bp[(ph * 4 + 2) * 64];
            long b3 = bp[(ph * 4 + 3) * 64];
            accA = __builtin_amdgcn_mfma_f32_32x32x16_fp8_fp8(afr[ph * 4 + 0], b0, accA, 0, 0, 0);
            accB = __builtin_amdgcn_mfma_f32_32x32x16_fp8_fp8(afr[ph * 4 + 1], b1, accB, 0, 0, 0);
            accC = __builtin_amdgcn_mfma_f32_32x32x16_fp8_fp8(afr[ph * 4 + 2], b2, accC, 0, 0, 0);
            accD = __builtin_amdgcn_mfma_f32_32x32x16_fp8_fp8(afr[ph * 4 + 3], b3, accD, 0, 0, 0);
        }
        __builtin_amdgcn_s_setprio(0);

        const float sb = sb_lds[c * 32 + col];   // ds_read (lgkmcnt, not vmcnt)
#pragma unroll
        for (int r = 0; r < 16; ++r)
            bs[r] = fmaxf(bs[r], (accA[r] + accB[r]) + (accC[r] + accD[r]) + sb);
    }

    // ---- Per-row max across the 32 col-lanes (masks<32 preserve hi2) ----
#pragma unroll
    for (int m = 1; m < 32; m <<= 1)
#pragma unroll
        for (int r = 0; r < 16; ++r)
            bs[r] = fmaxf(bs[r], __shfl_xor(bs[r], m, 64));

    // D rows: row = (r&3) + 8*(r>>2) + 4*hi2 — bijective over 32 rows per
    // (hi2, r); sum over all rows is mapping-invariant.
    if (col == 0) {
        float s = 0.f;
#pragma unroll
        for (int r = 0; r < 16; ++r) s += bs[r];
        gsum[wave * 2 + hi2] = s;
    }
    __syncthreads();
    if (threadIdx.x == 0) {
        float tot = 0.f;
#pragma unroll
        for (int i = 0; i < 2 * WAVES; ++i) tot += gsum[i];
        bpart[blockIdx.x] = tot;
    }
}

// loss = 0.25 * (Sxx - 2*sum_blocks bpart) / (65536*492)
__global__ __launch_bounds__(256) void finalize_k(const float* __restrict__ bpart,
                                                  const float* __restrict__ xsq_part,
                                                  float* __restrict__ out) {
    __shared__ double sm[256];
    int tid = threadIdx.x;
    sm[tid] = (double)bpart[tid];
    __syncthreads();
    for (int st = 128; st > 0; st >>= 1) {
        if (tid < st) sm[tid] += sm[tid + st];
        __syncthreads();
    }
    double S1 = sm[0];
    __syncthreads();
    sm[tid] = (double)xsq_part[tid];
    __syncthreads();
    for (int st = 128; st > 0; st >>= 1) {
        if (tid < st) sm[tid] += sm[tid + st];
        __syncthreads();
    }
    if (tid == 0)
        out[0] = (float)(0.25 * (sm[0] - 2.0 * S1) / ((double)MROWS * (double)DDIM));
}

extern "C" void kernel_launch(void* const* d_in, const int* in_sizes, int n_in,
                              void* d_out, int out_size, void* d_ws, size_t ws_size,
                              hipStream_t stream) {
    const float* x  = (const float*)d_in[0];   // (16,12,4096) f32
    const float* cb = (const float*)d_in[1];   // (1024,492) f32
    float* out = (float*)d_out;

    // workspace layout (~524 KiB)
    char* ws = (char*)d_ws;
    unsigned long long* bfrag = (unsigned long long*)ws;            // 512 KiB
    float* cnorm    = (float*)(ws + (512u << 10));                  // 4 KiB
    float* xsq_part = (float*)(ws + (512u << 10) + 4096);           // 1 KiB
    float* bpart    = (float*)(ws + (512u << 10) + 8192);           // 1 KiB

    prep_bfrag_k<<<256, 256, 0, stream>>>(cb, bfrag);
    prep_cnorm_k<<<KCODES, 64, 0, stream>>>(cb, cnorm);
    xsq_k<<<256, 256, 0, stream>>>(x, xsq_part);
    vq_main_k<<<NBLK, 512, 0, stream>>>(x, (const unsigned char*)bfrag, cnorm, bpart);
    finalize_k<<<1, 256, 0, stream>>>(bpart, xsq_part, out);
}